// Round 12
// baseline (6287.148 us; speedup 1.0000x reference)
//
#include <hip/hip_runtime.h>

// ---------------------------------------------------------------------------
// RecurrentActorCritic on MI355X.  B=128, T=256, F=128, H=256, 4H=1024, W=512, A=8.
// d_out (float): mean[1024] | log_std[8] | value[128] | c0n | h0n | c1n | h1n
//
// Round 12 = round 11 row-local design + one-line fix: rec_kernel's Zt read
// now includes the block's batch-row base (blk*16). Round 11 had every block
// consuming block 0's x@Wi contributions.
//
// Design recap: LSTM recurrence is row-local (never mixes batch rows), so each
// block owns 16 complete rows => NO cross-block sync. x@Wi hoisted into bulk
// GEMMs (Zt) per 64-step pass; rec kernel streams Wh from VGPR/LDS/L2; h is
// exchanged between waves via XOR-swizzled LDS. All ordering = kernel bounds.
// ---------------------------------------------------------------------------

typedef __attribute__((ext_vector_type(8))) short  frag8;   // 8 bf16 (4 VGPR)
typedef __attribute__((ext_vector_type(4))) float  f32x4;
typedef unsigned short u16;
typedef unsigned int   u32;

// workspace layout (bytes); peak 37.8MB (< 43.3MB proven in rounds 1-10)
#define WS_ZT    0                      // (64,1024,128) bf16 = 16MB ; P aliases
#define WS_WHB0  16777216               // Wh0 frag bf16 512KB
#define WS_WHB1  17301504               // Wh1 frag bf16 512KB
#define WS_YS0P  17825792               // (64,128,256) bf16 = 4.2MB (per pass)
#define WS_YS1   22020096               // (256,128,256) bf16 = 16.8MB
#define WS_C0S   38797312               // c0 state f32 (128,256)
#define WS_C1S   38928384
#define WS_H0M   39059456               // heads temporaries
#define WS_V1M   39321600

__device__ __forceinline__ u16 f2b(float f) {
  u32 u = __builtin_bit_cast(u32, f);
  u32 r = (u + 0x7fffu + ((u >> 16) & 1u)) >> 16;   // RNE
  return (u16)r;
}
__device__ __forceinline__ float b2f(u16 b) {
  return __builtin_bit_cast(float, (u32)b << 16);
}
__device__ __forceinline__ float sigm(float x) { return 1.0f / (1.0f + __expf(-x)); }
__device__ __forceinline__ float tanh_(float x) {
  x = fminf(fmaxf(x, -15.0f), 15.0f);
  float e = __expf(2.0f * x);
  return (e - 1.0f) / (e + 1.0f);
}

// ---------------- Wh -> frag-layout bf16 -----------------------------------
// frag id fi = (n*8 + kt)*64 + l ; n = w*8+ln, w=wave(8), ln: g=ln>>1, j=ln&1
// gcol = g*256 + w*32 + j*16 + (l&15) ; k = kt*32 + (l>>4)*8 + jj
__global__ void whb_kernel(const float* __restrict__ Wh0, const float* __restrict__ Wh1,
                           u16* __restrict__ whb0, u16* __restrict__ whb1) {
  int g = blockIdx.x * 256 + threadIdx.x;   // 65536 threads, 1 frag each
  int layer = g >> 15;
  int fi = g & 32767;
  int l = fi & 63, kt = (fi >> 6) & 7, n = fi >> 9;
  int w = n >> 3, ln = n & 7, gg = ln >> 1, j = ln & 1;
  int gcol = gg * 256 + w * 32 + j * 16 + (l & 15);
  int kb = kt * 32 + (l >> 4) * 8;
  const float* W = layer ? Wh1 : Wh0;
  u16* dst = (layer ? whb1 : whb0) + (size_t)fi * 8;
#pragma unroll
  for (int jj = 0; jj < 8; ++jj)
    dst[jj] = f2b(W[(size_t)(kb + jj) * 1024 + gcol]);
}

// ---------------- Z-GEMM: Zt = A @ Wi + bias (bf16 out, (trel,gcol,b)) -----
// grid 2048: mt = bx&255 (M-tile 32 of 8192 rows=(t,b)), nbt = bx>>8 (N-tile 128)
template <int SRCF32, int KDIM>
__launch_bounds__(256, 2)
__global__ void zgemm_kernel(const void* __restrict__ Asrc,
                             const float* __restrict__ W,    // (KDIM,1024)
                             const float* __restrict__ bias, // (1024)
                             u16* __restrict__ Zt, int t0) {
  const int bx = blockIdx.x;
  const int mt = bx & 255, nbt = bx >> 8;
  const int tid = threadIdx.x, wv = tid >> 6, l = tid & 63;
  const int wvM = wv >> 1, wvN = wv & 1;
  const int trel = (mt * 32) >> 7;
  const int b0r = (mt * 32) & 127;
  const int brow = b0r + wvM * 16 + (l & 15);
  const int t = t0 + trel;
  const int lk = (l >> 4) * 8;
  f32x4 acc[4] = {};
#pragma unroll 2
  for (int ks = 0; ks < KDIM / 32; ++ks) {
    int k0 = ks * 32;
    frag8 a;
    if (SRCF32) {
      const float* ap = (const float*)Asrc + ((size_t)(brow * 256 + t)) * 128 + k0 + lk;
      float4 q0 = *(const float4*)ap, q1 = *(const float4*)(ap + 4);
      a[0] = (short)f2b(q0.x); a[1] = (short)f2b(q0.y);
      a[2] = (short)f2b(q0.z); a[3] = (short)f2b(q0.w);
      a[4] = (short)f2b(q1.x); a[5] = (short)f2b(q1.y);
      a[6] = (short)f2b(q1.z); a[7] = (short)f2b(q1.w);
    } else {
      a = *(const frag8*)((const u16*)Asrc + ((size_t)(trel * 128 + brow)) * KDIM + k0 + lk);
    }
#pragma unroll
    for (int jn = 0; jn < 4; ++jn) {
      int gcol = nbt * 128 + wvN * 64 + jn * 16 + (l & 15);
      frag8 bf;
#pragma unroll
      for (int jj = 0; jj < 8; ++jj)
        bf[jj] = (short)f2b(W[(size_t)(k0 + lk + jj) * 1024 + gcol]);
      acc[jn] = __builtin_amdgcn_mfma_f32_16x16x32_bf16(a, bf, acc[jn], 0, 0, 0);
    }
  }
#pragma unroll
  for (int jn = 0; jn < 4; ++jn) {
    int gcol = nbt * 128 + wvN * 64 + jn * 16 + (l & 15);
    float bs = bias[gcol];
    ushort4 o;
    o.x = f2b(acc[jn][0] + bs); o.y = f2b(acc[jn][1] + bs);
    o.z = f2b(acc[jn][2] + bs); o.w = f2b(acc[jn][3] + bs);
    *(ushort4*)(Zt + ((size_t)trel * 1024 + gcol) * 128 + b0r + wvM * 16 + (l >> 4) * 4) = o;
  }
}

// ---------------- row-local LSTM recurrence (64 steps per launch) ----------
// 8 blocks x 512 threads (8 waves). Block owns rows [16*blk,16*blk+16).
// Wave w owns hd [32w,32w+32) = 8 ntiles (ln: g=ln>>1, j=ln&1).
// Weight tiers: ln 0-3 VGPR; ln==4 LDS (waves 0-5); rest streamed from L2.
__launch_bounds__(512, 1)
__global__ void rec_kernel(const u16* __restrict__ Zt,      // (64,1024,128) bf16
                           const u16* __restrict__ whb,     // frag layout
                           const float* __restrict__ cIn,   // p==0 initial c (f32)
                           const float* __restrict__ hIn,   // p==0 initial h (f32)
                           float* __restrict__ cS,          // c state (128,256) f32
                           const u16* __restrict__ hPrevT,  // h at t0-1 (bf16), p>0
                           u16* __restrict__ ysOut,         // base at t0, stride 32768
                           float* __restrict__ cOut, float* __restrict__ hOut,
                           int p0, int lastPass) {
  __shared__ u16 smem[28672];                 // 48KB weights + 8KB h (57344B)
  u16* smw = smem;                            // weights: frag (w<6, kt, l)
  char* smh = (char*)smem + 49152;            // h tile 16x256 bf16, XOR-swizzled

  const int tid = threadIdx.x, w = tid >> 6, l = tid & 63;
  const int blk = blockIdx.x;

  // stage LDS weights (ln==4 of waves 0..5), all 512 threads cooperate
  for (int i = tid; i < 3072; i += 512) {
    int wsrc = i >> 9, kt = (i >> 6) & 7, li = i & 63;
    const u16* src = whb + (((size_t)(wsrc * 8 + 4) * 8 + kt) * 64 + li) * 8;
    u16* dst = smw + ((size_t)(wsrc * 8 + kt) * 64 + li) * 8;
    *(ulonglong2*)dst = *(const ulonglong2*)src;
  }

  // resident weights: ln 0..3
  frag8 wres[4][8];
#pragma unroll
  for (int ln = 0; ln < 4; ++ln)
#pragma unroll
    for (int kt = 0; kt < 8; ++kt)
      wres[ln][kt] = *(const frag8*)(whb + (((size_t)(w * 8 + ln) * 8 + kt) * 64 + l) * 8);

  // c state: per lane 8 = (j 0..1, r 0..3); row=(l>>4)*4+r, hd=w*32+j*16+(l&15)
  float cst[8];
#pragma unroll
  for (int j = 0; j < 2; ++j)
#pragma unroll
    for (int r = 0; r < 4; ++r) {
      int row = blk * 16 + (l >> 4) * 4 + r, hd = w * 32 + j * 16 + (l & 15);
      cst[j * 4 + r] = p0 ? cIn[row * 256 + hd] : cS[row * 256 + hd];
    }

  // h A-frags: row = l&15, k-slice = kt*32 + (l>>4)*8
  frag8 ha[8];
  {
    int hrow = blk * 16 + (l & 15);
    if (p0) {
#pragma unroll
      for (int kt = 0; kt < 8; ++kt) {
        const float* p = hIn + hrow * 256 + kt * 32 + (l >> 4) * 8;
        float4 q0 = *(const float4*)p, q1 = *(const float4*)(p + 4);
        frag8 f;
        f[0] = (short)f2b(q0.x); f[1] = (short)f2b(q0.y);
        f[2] = (short)f2b(q0.z); f[3] = (short)f2b(q0.w);
        f[4] = (short)f2b(q1.x); f[5] = (short)f2b(q1.y);
        f[6] = (short)f2b(q1.z); f[7] = (short)f2b(q1.w);
        ha[kt] = f;
      }
    } else {
#pragma unroll
      for (int kt = 0; kt < 8; ++kt)
        ha[kt] = *(const frag8*)(hPrevT + hrow * 256 + kt * 32 + (l >> 4) * 8);
    }
  }
  __syncthreads();   // LDS weights staged

#pragma unroll 1
  for (int tr = 0; tr < 64; ++tr) {
    // acc init from Zt (x@Wi + bias, precomputed). ROUND-12 FIX: + blk*16.
    f32x4 acc[8];
#pragma unroll
    for (int ln = 0; ln < 8; ++ln) {
      int gcb = (ln >> 1) * 256 + w * 32 + (ln & 1) * 16;
      ushort4 z = *(const ushort4*)(Zt + ((size_t)tr * 1024 + gcb + (l & 15)) * 128
                                       + blk * 16 + (l >> 4) * 4);
      acc[ln] = f32x4{b2f(z.x), b2f(z.y), b2f(z.z), b2f(z.w)};
    }
    // h @ Wh
#pragma unroll
    for (int ln = 0; ln < 8; ++ln) {
#pragma unroll
      for (int kt = 0; kt < 8; ++kt) {
        frag8 bf;
        if (ln < 4)            bf = wres[ln][kt];
        else if (ln == 4 && w < 6)
          bf = *(const frag8*)(smw + ((size_t)(w * 8 + kt) * 64 + l) * 8);
        else
          bf = *(const frag8*)(whb + (((size_t)(w * 8 + ln) * 8 + kt) * 64 + l) * 8);
        acc[ln] = __builtin_amdgcn_mfma_f32_16x16x32_bf16(ha[kt], bf, acc[ln], 0, 0, 0);
      }
    }

    __syncthreads();   // all waves done reading previous h from LDS

    // gates; zi=acc[j], zf=acc[2+j], zg=acc[4+j], zo=acc[6+j]
#pragma unroll
    for (int j = 0; j < 2; ++j)
#pragma unroll
      for (int r = 0; r < 4; ++r) {
        float zi = acc[0 + j][r], zf = acc[2 + j][r];
        float zg = acc[4 + j][r], zo = acc[6 + j][r];
        float cn = sigm(zf) * cst[j * 4 + r] + sigm(zi) * tanh_(zg);
        float hn = sigm(zo) * tanh_(cn);
        cst[j * 4 + r] = cn;
        u16 hb = f2b(hn);
        int rowl = (l >> 4) * 4 + r;
        int hd = w * 32 + j * 16 + (l & 15);
        ysOut[(size_t)tr * 32768 + (blk * 16 + rowl) * 256 + hd] = hb;
        int byte = (rowl * 512 + hd * 2) ^ ((rowl & 7) << 4);
        *(u16*)(smh + byte) = hb;
        if (lastPass && tr == 63) {
          cOut[(blk * 16 + rowl) * 256 + hd] = cn;
          hOut[(blk * 16 + rowl) * 256 + hd] = hn;
        }
      }
    __syncthreads();   // h_t visible in LDS

    // rebuild A-frags for next step (swizzled 16B reads)
#pragma unroll
    for (int kt = 0; kt < 8; ++kt) {
      int row = l & 15;
      int byte = (row * 512 + (kt * 32 + (l >> 4) * 8) * 2) ^ ((row & 7) << 4);
      ha[kt] = *(const frag8*)(smh + byte);
    }
  }

  // persist c state
#pragma unroll
  for (int j = 0; j < 2; ++j)
#pragma unroll
    for (int r = 0; r < 4; ++r) {
      int row = blk * 16 + (l >> 4) * 4 + r, hd = w * 32 + j * 16 + (l & 15);
      cS[row * 256 + hd] = cst[j * 4 + r];
    }
}

// ---------------- heads (validated rounds 1-10) ----------------------------
__launch_bounds__(256, 2)
__global__ void head_gemm_kernel(const u16* __restrict__ flatT,
                                 const float* __restrict__ Wv0,
                                 const float* __restrict__ Wm0,
                                 float* __restrict__ P) {
  const int bx = blockIdx.x;
  const int nb = bx >> 5, kb = bx & 31;
  const float* W = (nb >> 3) ? Wm0 : Wv0;
  const int ncb = (nb & 7) * 64;
  const int tid = threadIdx.x;
  const int wv = tid >> 6, l = tid & 63;
  const int lrow = l & 15, lk = (l >> 4) * 8;
  f32x4 acc[2][4] = {};
  const int kbase = kb * 2048;
#pragma unroll 2
  for (int ks = 0; ks < 64; ++ks) {
    int k0 = kbase + ks * 32;
    int t = k0 >> 8, h = k0 & 255;
    frag8 a[2];
#pragma unroll
    for (int mi = 0; mi < 2; ++mi) {
      int row = (2 * wv + mi) * 16 + lrow;
      a[mi] = *reinterpret_cast<const frag8*>(flatT + ((size_t)t * 128 + row) * 256 + h + lk);
    }
#pragma unroll
    for (int nt = 0; nt < 4; ++nt) {
      int col = ncb + nt * 16 + lrow;
      const float* wp = W + (size_t)(k0 + lk) * 512 + col;
      frag8 bfrag;
#pragma unroll
      for (int j = 0; j < 8; ++j) bfrag[j] = (short)f2b(wp[(size_t)j * 512]);
      acc[0][nt] = __builtin_amdgcn_mfma_f32_16x16x32_bf16(a[0], bfrag, acc[0][nt], 0, 0, 0);
      acc[1][nt] = __builtin_amdgcn_mfma_f32_16x16x32_bf16(a[1], bfrag, acc[1][nt], 0, 0, 0);
    }
  }
  float* Pb = P + (size_t)bx * 8192;
#pragma unroll
  for (int mi = 0; mi < 2; ++mi)
#pragma unroll
    for (int nt = 0; nt < 4; ++nt)
#pragma unroll
      for (int r = 0; r < 4; ++r) {
        int row = (2 * wv + mi) * 16 + (l >> 4) * 4 + r;
        int nl = nt * 16 + lrow;
        Pb[row * 64 + nl] = acc[mi][nt][r];
      }
}

__global__ void head_reduce_kernel(const float* __restrict__ P,
                                   const float* __restrict__ bv0,
                                   const float* __restrict__ bm0,
                                   u16* __restrict__ H0) {
  int o = blockIdx.x * 256 + threadIdx.x;
  int row = o >> 10, gcol = o & 1023;
  int nb = gcol >> 6, nl = gcol & 63;
  float s = 0.f;
#pragma unroll
  for (int kb = 0; kb < 32; ++kb)
    s += P[(size_t)(nb * 32 + kb) * 8192 + row * 64 + nl];
  s += (gcol < 512) ? bv0[gcol] : bm0[gcol - 512];
  H0[row * 1024 + gcol] = f2b(tanh_(s));
}

__launch_bounds__(256, 2)
__global__ void head_mid_kernel(const u16* __restrict__ H0,
                                const float* __restrict__ Wv1,
                                const float* __restrict__ Wm1,
                                const float* __restrict__ bv1,
                                const float* __restrict__ bm1,
                                u16* __restrict__ V1M) {
  const int nb = blockIdx.x;
  const int head = nb >> 3;
  const int ncb = (nb & 7) * 64;
  const float* W = head ? Wm1 : Wv1;
  const float* bsrc = head ? bm1 : bv1;
  const int tid = threadIdx.x, wv = tid >> 6, l = tid & 63;
  const int lrow = l & 15, lk = (l >> 4) * 8;
  const int aoff = head * 512;
  f32x4 acc[2][4] = {};
#pragma unroll 2
  for (int ks = 0; ks < 16; ++ks) {
    int k0 = ks * 32;
    frag8 a[2];
#pragma unroll
    for (int mi = 0; mi < 2; ++mi) {
      int row = (2 * wv + mi) * 16 + lrow;
      a[mi] = *reinterpret_cast<const frag8*>(H0 + row * 1024 + aoff + k0 + lk);
    }
#pragma unroll
    for (int nt = 0; nt < 4; ++nt) {
      int col = ncb + nt * 16 + lrow;
      const float* wp = W + (size_t)(k0 + lk) * 512 + col;
      frag8 bfrag;
#pragma unroll
      for (int j = 0; j < 8; ++j) bfrag[j] = (short)f2b(wp[(size_t)j * 512]);
      acc[0][nt] = __builtin_amdgcn_mfma_f32_16x16x32_bf16(a[0], bfrag, acc[0][nt], 0, 0, 0);
      acc[1][nt] = __builtin_amdgcn_mfma_f32_16x16x32_bf16(a[1], bfrag, acc[1][nt], 0, 0, 0);
    }
  }
#pragma unroll
  for (int mi = 0; mi < 2; ++mi)
#pragma unroll
    for (int nt = 0; nt < 4; ++nt)
#pragma unroll
      for (int r = 0; r < 4; ++r) {
        int row = (2 * wv + mi) * 16 + (l >> 4) * 4 + r;
        int cl = ncb + nt * 16 + lrow;
        float z = acc[mi][nt][r] + bsrc[cl];
        V1M[row * 1024 + head * 512 + cl] = f2b(tanh_(z));
      }
}

__global__ void head_final_kernel(const u16* __restrict__ V1M,
                                  const float* __restrict__ Wv2,
                                  const float* __restrict__ bv2,
                                  const float* __restrict__ Wm2,
                                  const float* __restrict__ bm2,
                                  const float* __restrict__ log_std,
                                  float* __restrict__ out) {
  int tid = threadIdx.x;   // 1024 threads
  {
    int row = tid >> 3, a = tid & 7;
    float s = 0.f;
    for (int k = 0; k < 512; ++k)
      s += b2f(V1M[row * 1024 + 512 + k]) * Wm2[k * 8 + a];
    out[row * 8 + a] = s + bm2[a];
  }
  if (tid < 128) {
    float s = 0.f;
    for (int k = 0; k < 512; ++k)
      s += b2f(V1M[tid * 1024 + k]) * Wv2[k];
    out[1032 + tid] = s + bv2[0];
  }
  if (tid < 8) out[1024 + tid] = log_std[tid];
}

// ---------------------------------------------------------------------------
extern "C" void kernel_launch(void* const* d_in, const int* in_sizes, int n_in,
                              void* d_out, int out_size, void* d_ws, size_t ws_size,
                              hipStream_t stream) {
  const float* x    = (const float*)d_in[0];
  const float* c0   = (const float*)d_in[1];
  const float* h0   = (const float*)d_in[2];
  const float* c1   = (const float*)d_in[3];
  const float* h1   = (const float*)d_in[4];
  const float* Wi0  = (const float*)d_in[5];
  const float* Wh0  = (const float*)d_in[6];
  const float* b0   = (const float*)d_in[7];
  const float* Wi1  = (const float*)d_in[8];
  const float* Wh1  = (const float*)d_in[9];
  const float* b1   = (const float*)d_in[10];
  const float* Wv0  = (const float*)d_in[11];
  const float* bv0  = (const float*)d_in[12];
  const float* Wv1  = (const float*)d_in[13];
  const float* bv1  = (const float*)d_in[14];
  const float* Wv2  = (const float*)d_in[15];
  const float* bv2  = (const float*)d_in[16];
  const float* Wm0  = (const float*)d_in[17];
  const float* bm0  = (const float*)d_in[18];
  const float* Wm1  = (const float*)d_in[19];
  const float* bm1  = (const float*)d_in[20];
  const float* Wm2  = (const float*)d_in[21];
  const float* bm2  = (const float*)d_in[22];
  const float* lstd = (const float*)d_in[23];
  float* out = (float*)d_out;
  char* ws = (char*)d_ws;

  u16* Zt    = (u16*)(ws + WS_ZT);
  u16* whb0  = (u16*)(ws + WS_WHB0);
  u16* whb1  = (u16*)(ws + WS_WHB1);
  u16* ys0p  = (u16*)(ws + WS_YS0P);
  u16* ys1   = (u16*)(ws + WS_YS1);
  float* c0S = (float*)(ws + WS_C0S);
  float* c1S = (float*)(ws + WS_C1S);
  u16* H0M   = (u16*)(ws + WS_H0M);
  u16* V1M   = (u16*)(ws + WS_V1M);
  float* P   = (float*)(ws + WS_ZT);    // aliases Zt (dead at head time)

  whb_kernel<<<256, 256, 0, stream>>>(Wh0, Wh1, whb0, whb1);

  for (int p = 0; p < 4; ++p) {
    int t0 = p * 64;
    zgemm_kernel<1, 128><<<2048, 256, 0, stream>>>(x, Wi0, b0, Zt, t0);
    rec_kernel<<<8, 512, 0, stream>>>(Zt, whb0, c0, h0, c0S,
                                      ys0p + (size_t)63 * 32768, ys0p,
                                      out + 1160, out + 33928, p == 0, p == 3);
    zgemm_kernel<0, 256><<<2048, 256, 0, stream>>>(ys0p, Wi1, b1, Zt, t0);
    rec_kernel<<<8, 512, 0, stream>>>(Zt, whb1, c1, h1, c1S,
                                      (p == 0) ? ys1 : ys1 + (size_t)(t0 - 1) * 32768,
                                      ys1 + (size_t)t0 * 32768,
                                      out + 66696, out + 99464, p == 0, p == 3);
  }

  head_gemm_kernel<<<512, 256, 0, stream>>>(ys1, Wv0, Wm0, P);
  head_reduce_kernel<<<512, 256, 0, stream>>>(P, bv0, bm0, H0M);
  head_mid_kernel<<<16, 256, 0, stream>>>(H0M, Wv1, Wm1, bv1, bm1, V1M);
  head_final_kernel<<<1, 1024, 0, stream>>>(V1M, Wv2, bv2, Wm2, bm2, lstd, out);
}

// Round 13
// 6052.406 us; speedup vs baseline: 1.0388x; 1.0388x over previous
//
#include <hip/hip_runtime.h>

// ---------------------------------------------------------------------------
// RecurrentActorCritic on MI355X.  B=128, T=256, F=128, H=256, 4H=1024, W=512, A=8.
// d_out (float): mean[1024] | log_std[8] | value[128] | c0n | h0n | c1n | h1n
//
// Round 13 = round 12 row-local design (PASSED) + three rec-kernel fixes:
//  1) wres pinned via empty asm ("+v") so the compiler cannot rematerialize
//     the per-wave resident weights (r12: VGPR=128 proved wres was re-loaded
//     from L2/HBM every step -> 512KB/step traffic).
//  2) Zt layout is now block-contiguous (trel, b>>4, gcol, b&15): rec's Z
//     read is fully coalesced (512B/wave), no half-line waste.
//  3) Z single-buffer prefetch: step t+1's Z loads issue right after step t's
//     acc init -> HBM first-touch latency hides under MFMA + weight stream.
// ---------------------------------------------------------------------------

typedef __attribute__((ext_vector_type(8))) short  frag8;   // 8 bf16 (4 VGPR)
typedef __attribute__((ext_vector_type(4))) float  f32x4;
typedef unsigned short u16;
typedef unsigned int   u32;

// workspace layout (bytes); peak 37.8MB
#define WS_ZT    0                      // (64,8,1024,16) bf16 = 16MB ; P aliases
#define WS_WHB0  16777216               // Wh0 frag bf16 512KB
#define WS_WHB1  17301504               // Wh1 frag bf16 512KB
#define WS_YS0P  17825792               // (64,128,256) bf16 = 4.2MB (per pass)
#define WS_YS1   22020096               // (256,128,256) bf16 = 16.8MB
#define WS_C0S   38797312               // c0 state f32 (128,256)
#define WS_C1S   38928384
#define WS_H0M   39059456               // heads temporaries
#define WS_V1M   39321600

__device__ __forceinline__ u16 f2b(float f) {
  u32 u = __builtin_bit_cast(u32, f);
  u32 r = (u + 0x7fffu + ((u >> 16) & 1u)) >> 16;   // RNE
  return (u16)r;
}
__device__ __forceinline__ float b2f(u16 b) {
  return __builtin_bit_cast(float, (u32)b << 16);
}
__device__ __forceinline__ float sigm(float x) { return 1.0f / (1.0f + __expf(-x)); }
__device__ __forceinline__ float tanh_(float x) {
  x = fminf(fmaxf(x, -15.0f), 15.0f);
  float e = __expf(2.0f * x);
  return (e - 1.0f) / (e + 1.0f);
}

// ---------------- Wh -> frag-layout bf16 -----------------------------------
// frag id fi = (n*8 + kt)*64 + l ; n = w*8+ln, w=wave(8), ln: g=ln>>1, j=ln&1
// gcol = g*256 + w*32 + j*16 + (l&15) ; k = kt*32 + (l>>4)*8 + jj
__global__ void whb_kernel(const float* __restrict__ Wh0, const float* __restrict__ Wh1,
                           u16* __restrict__ whb0, u16* __restrict__ whb1) {
  int g = blockIdx.x * 256 + threadIdx.x;   // 65536 threads, 1 frag each
  int layer = g >> 15;
  int fi = g & 32767;
  int l = fi & 63, kt = (fi >> 6) & 7, n = fi >> 9;
  int w = n >> 3, ln = n & 7, gg = ln >> 1, j = ln & 1;
  int gcol = gg * 256 + w * 32 + j * 16 + (l & 15);
  int kb = kt * 32 + (l >> 4) * 8;
  const float* W = layer ? Wh1 : Wh0;
  u16* dst = (layer ? whb1 : whb0) + (size_t)fi * 8;
#pragma unroll
  for (int jj = 0; jj < 8; ++jj)
    dst[jj] = f2b(W[(size_t)(kb + jj) * 1024 + gcol]);
}

// ---------------- Z-GEMM: Zt = A @ Wi + bias (bf16, (trel,bb,gcol,bl)) -----
// grid 2048: mt = bx&255 (M-tile 32 of 8192 rows=(t,b)), nbt = bx>>8 (N-tile 128)
template <int SRCF32, int KDIM>
__launch_bounds__(256, 2)
__global__ void zgemm_kernel(const void* __restrict__ Asrc,
                             const float* __restrict__ W,    // (KDIM,1024)
                             const float* __restrict__ bias, // (1024)
                             u16* __restrict__ Zt, int t0) {
  const int bx = blockIdx.x;
  const int mt = bx & 255, nbt = bx >> 8;
  const int tid = threadIdx.x, wv = tid >> 6, l = tid & 63;
  const int wvM = wv >> 1, wvN = wv & 1;
  const int trel = (mt * 32) >> 7;
  const int b0r = (mt * 32) & 127;
  const int brow = b0r + wvM * 16 + (l & 15);
  const int t = t0 + trel;
  const int lk = (l >> 4) * 8;
  f32x4 acc[4] = {};
#pragma unroll 2
  for (int ks = 0; ks < KDIM / 32; ++ks) {
    int k0 = ks * 32;
    frag8 a;
    if (SRCF32) {
      const float* ap = (const float*)Asrc + ((size_t)(brow * 256 + t)) * 128 + k0 + lk;
      float4 q0 = *(const float4*)ap, q1 = *(const float4*)(ap + 4);
      a[0] = (short)f2b(q0.x); a[1] = (short)f2b(q0.y);
      a[2] = (short)f2b(q0.z); a[3] = (short)f2b(q0.w);
      a[4] = (short)f2b(q1.x); a[5] = (short)f2b(q1.y);
      a[6] = (short)f2b(q1.z); a[7] = (short)f2b(q1.w);
    } else {
      a = *(const frag8*)((const u16*)Asrc + ((size_t)(trel * 128 + brow)) * KDIM + k0 + lk);
    }
#pragma unroll
    for (int jn = 0; jn < 4; ++jn) {
      int gcol = nbt * 128 + wvN * 64 + jn * 16 + (l & 15);
      frag8 bf;
#pragma unroll
      for (int jj = 0; jj < 8; ++jj)
        bf[jj] = (short)f2b(W[(size_t)(k0 + lk + jj) * 1024 + gcol]);
      acc[jn] = __builtin_amdgcn_mfma_f32_16x16x32_bf16(a, bf, acc[jn], 0, 0, 0);
    }
  }
  const int bb = (b0r + wvM * 16) >> 4;            // batch block 0..7
#pragma unroll
  for (int jn = 0; jn < 4; ++jn) {
    int gcol = nbt * 128 + wvN * 64 + jn * 16 + (l & 15);
    float bs = bias[gcol];
    ushort4 o;
    o.x = f2b(acc[jn][0] + bs); o.y = f2b(acc[jn][1] + bs);
    o.z = f2b(acc[jn][2] + bs); o.w = f2b(acc[jn][3] + bs);
    *(ushort4*)(Zt + (((size_t)trel * 8 + bb) * 1024 + gcol) * 16 + (l >> 4) * 4) = o;
  }
}

// ---------------- row-local LSTM recurrence (64 steps per launch) ----------
// 8 blocks x 512 threads (8 waves). Block owns rows [16*blk,16*blk+16).
// Wave w owns hd [32w,32w+32) = 8 ntiles (ln: g=ln>>1, j=ln&1).
// Weight tiers: ln 0-3 VGPR (pinned); ln==4 LDS (waves 0-5); rest L2-streamed.
__launch_bounds__(512, 2)
__global__ void rec_kernel(const u16* __restrict__ Zt,      // (64,8,1024,16) bf16
                           const u16* __restrict__ whb,     // frag layout
                           const float* __restrict__ cIn,   // p==0 initial c (f32)
                           const float* __restrict__ hIn,   // p==0 initial h (f32)
                           float* __restrict__ cS,          // c state (128,256) f32
                           const u16* __restrict__ hPrevT,  // h at t0-1 (bf16), p>0
                           u16* __restrict__ ysOut,         // base at t0, stride 32768
                           float* __restrict__ cOut, float* __restrict__ hOut,
                           int p0, int lastPass) {
  __shared__ u16 smem[28672];                 // 48KB weights + 8KB h (57344B)
  u16* smw = smem;                            // weights: frag (w<6, kt, l)
  char* smh = (char*)smem + 49152;            // h tile 16x256 bf16, XOR-swizzled

  const int tid = threadIdx.x, w = tid >> 6, l = tid & 63;
  const int blk = blockIdx.x;

  // stage LDS weights (ln==4 of waves 0..5), all 512 threads cooperate
  for (int i = tid; i < 3072; i += 512) {
    int wsrc = i >> 9, kt = (i >> 6) & 7, li = i & 63;
    const u16* src = whb + (((size_t)(wsrc * 8 + 4) * 8 + kt) * 64 + li) * 8;
    u16* dst = smw + ((size_t)(wsrc * 8 + kt) * 64 + li) * 8;
    *(ulonglong2*)dst = *(const ulonglong2*)src;
  }

  // resident weights: ln 0..3, PINNED so the compiler cannot rematerialize
  frag8 wres[4][8];
#pragma unroll
  for (int ln = 0; ln < 4; ++ln)
#pragma unroll
    for (int kt = 0; kt < 8; ++kt) {
      wres[ln][kt] = *(const frag8*)(whb + (((size_t)(w * 8 + ln) * 8 + kt) * 64 + l) * 8);
      asm volatile("" : "+v"(wres[ln][kt]));
    }

  // c state: per lane 8 = (j 0..1, r 0..3); row=(l>>4)*4+r, hd=w*32+j*16+(l&15)
  float cst[8];
#pragma unroll
  for (int j = 0; j < 2; ++j)
#pragma unroll
    for (int r = 0; r < 4; ++r) {
      int row = blk * 16 + (l >> 4) * 4 + r, hd = w * 32 + j * 16 + (l & 15);
      cst[j * 4 + r] = p0 ? cIn[row * 256 + hd] : cS[row * 256 + hd];
    }

  // h A-frags: row = l&15, k-slice = kt*32 + (l>>4)*8
  frag8 ha[8];
  {
    int hrow = blk * 16 + (l & 15);
    if (p0) {
#pragma unroll
      for (int kt = 0; kt < 8; ++kt) {
        const float* p = hIn + hrow * 256 + kt * 32 + (l >> 4) * 8;
        float4 q0 = *(const float4*)p, q1 = *(const float4*)(p + 4);
        frag8 f;
        f[0] = (short)f2b(q0.x); f[1] = (short)f2b(q0.y);
        f[2] = (short)f2b(q0.z); f[3] = (short)f2b(q0.w);
        f[4] = (short)f2b(q1.x); f[5] = (short)f2b(q1.y);
        f[6] = (short)f2b(q1.z); f[7] = (short)f2b(q1.w);
        ha[kt] = f;
      }
    } else {
#pragma unroll
      for (int kt = 0; kt < 8; ++kt)
        ha[kt] = *(const frag8*)(hPrevT + hrow * 256 + kt * 32 + (l >> 4) * 8);
    }
  }

  // Z prefetch for tr=0 (block-contiguous layout, fully coalesced)
  ushort4 zr[8];
#pragma unroll
  for (int ln = 0; ln < 8; ++ln) {
    int gcb = (ln >> 1) * 256 + w * 32 + (ln & 1) * 16;
    zr[ln] = *(const ushort4*)(Zt + (((size_t)blk) * 1024 + gcb + (l & 15)) * 16 + (l >> 4) * 4);
  }
  __syncthreads();   // LDS weights staged

#pragma unroll 1
  for (int tr = 0; tr < 64; ++tr) {
    // acc init from prefetched Z, then immediately prefetch tr+1
    f32x4 acc[8];
#pragma unroll
    for (int ln = 0; ln < 8; ++ln)
      acc[ln] = f32x4{b2f(zr[ln].x), b2f(zr[ln].y), b2f(zr[ln].z), b2f(zr[ln].w)};
    if (tr < 63) {
#pragma unroll
      for (int ln = 0; ln < 8; ++ln) {
        int gcb = (ln >> 1) * 256 + w * 32 + (ln & 1) * 16;
        zr[ln] = *(const ushort4*)(Zt + (((size_t)(tr + 1) * 8 + blk) * 1024 + gcb + (l & 15)) * 16
                                      + (l >> 4) * 4);
      }
    }

    // h @ Wh
#pragma unroll
    for (int ln = 0; ln < 8; ++ln) {
#pragma unroll
      for (int kt = 0; kt < 8; ++kt) {
        frag8 bf;
        if (ln < 4)            bf = wres[ln][kt];
        else if (ln == 4 && w < 6)
          bf = *(const frag8*)(smw + ((size_t)(w * 8 + kt) * 64 + l) * 8);
        else
          bf = *(const frag8*)(whb + (((size_t)(w * 8 + ln) * 8 + kt) * 64 + l) * 8);
        acc[ln] = __builtin_amdgcn_mfma_f32_16x16x32_bf16(ha[kt], bf, acc[ln], 0, 0, 0);
      }
    }

    __syncthreads();   // all waves done reading previous h from LDS

    // gates; zi=acc[j], zf=acc[2+j], zg=acc[4+j], zo=acc[6+j]
#pragma unroll
    for (int j = 0; j < 2; ++j)
#pragma unroll
      for (int r = 0; r < 4; ++r) {
        float zi = acc[0 + j][r], zf = acc[2 + j][r];
        float zg = acc[4 + j][r], zo = acc[6 + j][r];
        float cn = sigm(zf) * cst[j * 4 + r] + sigm(zi) * tanh_(zg);
        float hn = sigm(zo) * tanh_(cn);
        cst[j * 4 + r] = cn;
        u16 hb = f2b(hn);
        int rowl = (l >> 4) * 4 + r;
        int hd = w * 32 + j * 16 + (l & 15);
        ysOut[(size_t)tr * 32768 + (blk * 16 + rowl) * 256 + hd] = hb;
        int byte = (rowl * 512 + hd * 2) ^ ((rowl & 7) << 4);
        *(u16*)(smh + byte) = hb;
        if (lastPass && tr == 63) {
          cOut[(blk * 16 + rowl) * 256 + hd] = cn;
          hOut[(blk * 16 + rowl) * 256 + hd] = hn;
        }
      }
    __syncthreads();   // h_t visible in LDS

    // rebuild A-frags for next step (swizzled 16B reads)
#pragma unroll
    for (int kt = 0; kt < 8; ++kt) {
      int row = l & 15;
      int byte = (row * 512 + (kt * 32 + (l >> 4) * 8) * 2) ^ ((row & 7) << 4);
      ha[kt] = *(const frag8*)(smh + byte);
    }
  }

  // persist c state
#pragma unroll
  for (int j = 0; j < 2; ++j)
#pragma unroll
    for (int r = 0; r < 4; ++r) {
      int row = blk * 16 + (l >> 4) * 4 + r, hd = w * 32 + j * 16 + (l & 15);
      cS[row * 256 + hd] = cst[j * 4 + r];
    }
}

// ---------------- heads (validated rounds 1-12) ----------------------------
__launch_bounds__(256, 2)
__global__ void head_gemm_kernel(const u16* __restrict__ flatT,
                                 const float* __restrict__ Wv0,
                                 const float* __restrict__ Wm0,
                                 float* __restrict__ P) {
  const int bx = blockIdx.x;
  const int nb = bx >> 5, kb = bx & 31;
  const float* W = (nb >> 3) ? Wm0 : Wv0;
  const int ncb = (nb & 7) * 64;
  const int tid = threadIdx.x;
  const int wv = tid >> 6, l = tid & 63;
  const int lrow = l & 15, lk = (l >> 4) * 8;
  f32x4 acc[2][4] = {};
  const int kbase = kb * 2048;
#pragma unroll 2
  for (int ks = 0; ks < 64; ++ks) {
    int k0 = kbase + ks * 32;
    int t = k0 >> 8, h = k0 & 255;
    frag8 a[2];
#pragma unroll
    for (int mi = 0; mi < 2; ++mi) {
      int row = (2 * wv + mi) * 16 + lrow;
      a[mi] = *reinterpret_cast<const frag8*>(flatT + ((size_t)t * 128 + row) * 256 + h + lk);
    }
#pragma unroll
    for (int nt = 0; nt < 4; ++nt) {
      int col = ncb + nt * 16 + lrow;
      const float* wp = W + (size_t)(k0 + lk) * 512 + col;
      frag8 bfrag;
#pragma unroll
      for (int j = 0; j < 8; ++j) bfrag[j] = (short)f2b(wp[(size_t)j * 512]);
      acc[0][nt] = __builtin_amdgcn_mfma_f32_16x16x32_bf16(a[0], bfrag, acc[0][nt], 0, 0, 0);
      acc[1][nt] = __builtin_amdgcn_mfma_f32_16x16x32_bf16(a[1], bfrag, acc[1][nt], 0, 0, 0);
    }
  }
  float* Pb = P + (size_t)bx * 8192;
#pragma unroll
  for (int mi = 0; mi < 2; ++mi)
#pragma unroll
    for (int nt = 0; nt < 4; ++nt)
#pragma unroll
      for (int r = 0; r < 4; ++r) {
        int row = (2 * wv + mi) * 16 + (l >> 4) * 4 + r;
        int nl = nt * 16 + lrow;
        Pb[row * 64 + nl] = acc[mi][nt][r];
      }
}

__global__ void head_reduce_kernel(const float* __restrict__ P,
                                   const float* __restrict__ bv0,
                                   const float* __restrict__ bm0,
                                   u16* __restrict__ H0) {
  int o = blockIdx.x * 256 + threadIdx.x;
  int row = o >> 10, gcol = o & 1023;
  int nb = gcol >> 6, nl = gcol & 63;
  float s = 0.f;
#pragma unroll
  for (int kb = 0; kb < 32; ++kb)
    s += P[(size_t)(nb * 32 + kb) * 8192 + row * 64 + nl];
  s += (gcol < 512) ? bv0[gcol] : bm0[gcol - 512];
  H0[row * 1024 + gcol] = f2b(tanh_(s));
}

__launch_bounds__(256, 2)
__global__ void head_mid_kernel(const u16* __restrict__ H0,
                                const float* __restrict__ Wv1,
                                const float* __restrict__ Wm1,
                                const float* __restrict__ bv1,
                                const float* __restrict__ bm1,
                                u16* __restrict__ V1M) {
  const int nb = blockIdx.x;
  const int head = nb >> 3;
  const int ncb = (nb & 7) * 64;
  const float* W = head ? Wm1 : Wv1;
  const float* bsrc = head ? bm1 : bv1;
  const int tid = threadIdx.x, wv = tid >> 6, l = tid & 63;
  const int lrow = l & 15, lk = (l >> 4) * 8;
  const int aoff = head * 512;
  f32x4 acc[2][4] = {};
#pragma unroll 2
  for (int ks = 0; ks < 16; ++ks) {
    int k0 = ks * 32;
    frag8 a[2];
#pragma unroll
    for (int mi = 0; mi < 2; ++mi) {
      int row = (2 * wv + mi) * 16 + lrow;
      a[mi] = *reinterpret_cast<const frag8*>(H0 + row * 1024 + aoff + k0 + lk);
    }
#pragma unroll
    for (int nt = 0; nt < 4; ++nt) {
      int col = ncb + nt * 16 + lrow;
      const float* wp = W + (size_t)(k0 + lk) * 512 + col;
      frag8 bfrag;
#pragma unroll
      for (int j = 0; j < 8; ++j) bfrag[j] = (short)f2b(wp[(size_t)j * 512]);
      acc[0][nt] = __builtin_amdgcn_mfma_f32_16x16x32_bf16(a[0], bfrag, acc[0][nt], 0, 0, 0);
      acc[1][nt] = __builtin_amdgcn_mfma_f32_16x16x32_bf16(a[1], bfrag, acc[1][nt], 0, 0, 0);
    }
  }
#pragma unroll
  for (int mi = 0; mi < 2; ++mi)
#pragma unroll
    for (int nt = 0; nt < 4; ++nt)
#pragma unroll
      for (int r = 0; r < 4; ++r) {
        int row = (2 * wv + mi) * 16 + (l >> 4) * 4 + r;
        int cl = ncb + nt * 16 + lrow;
        float z = acc[mi][nt][r] + bsrc[cl];
        V1M[row * 1024 + head * 512 + cl] = f2b(tanh_(z));
      }
}

__global__ void head_final_kernel(const u16* __restrict__ V1M,
                                  const float* __restrict__ Wv2,
                                  const float* __restrict__ bv2,
                                  const float* __restrict__ Wm2,
                                  const float* __restrict__ bm2,
                                  const float* __restrict__ log_std,
                                  float* __restrict__ out) {
  int tid = threadIdx.x;   // 1024 threads
  {
    int row = tid >> 3, a = tid & 7;
    float s = 0.f;
    for (int k = 0; k < 512; ++k)
      s += b2f(V1M[row * 1024 + 512 + k]) * Wm2[k * 8 + a];
    out[row * 8 + a] = s + bm2[a];
  }
  if (tid < 128) {
    float s = 0.f;
    for (int k = 0; k < 512; ++k)
      s += b2f(V1M[tid * 1024 + k]) * Wv2[k];
    out[1032 + tid] = s + bv2[0];
  }
  if (tid < 8) out[1024 + tid] = log_std[tid];
}

// ---------------------------------------------------------------------------
extern "C" void kernel_launch(void* const* d_in, const int* in_sizes, int n_in,
                              void* d_out, int out_size, void* d_ws, size_t ws_size,
                              hipStream_t stream) {
  const float* x    = (const float*)d_in[0];
  const float* c0   = (const float*)d_in[1];
  const float* h0   = (const float*)d_in[2];
  const float* c1   = (const float*)d_in[3];
  const float* h1   = (const float*)d_in[4];
  const float* Wi0  = (const float*)d_in[5];
  const float* Wh0  = (const float*)d_in[6];
  const float* b0   = (const float*)d_in[7];
  const float* Wi1  = (const float*)d_in[8];
  const float* Wh1  = (const float*)d_in[9];
  const float* b1   = (const float*)d_in[10];
  const float* Wv0  = (const float*)d_in[11];
  const float* bv0  = (const float*)d_in[12];
  const float* Wv1  = (const float*)d_in[13];
  const float* bv1  = (const float*)d_in[14];
  const float* Wv2  = (const float*)d_in[15];
  const float* bv2  = (const float*)d_in[16];
  const float* Wm0  = (const float*)d_in[17];
  const float* bm0  = (const float*)d_in[18];
  const float* Wm1  = (const float*)d_in[19];
  const float* bm1  = (const float*)d_in[20];
  const float* Wm2  = (const float*)d_in[21];
  const float* bm2  = (const float*)d_in[22];
  const float* lstd = (const float*)d_in[23];
  float* out = (float*)d_out;
  char* ws = (char*)d_ws;

  u16* Zt    = (u16*)(ws + WS_ZT);
  u16* whb0  = (u16*)(ws + WS_WHB0);
  u16* whb1  = (u16*)(ws + WS_WHB1);
  u16* ys0p  = (u16*)(ws + WS_YS0P);
  u16* ys1   = (u16*)(ws + WS_YS1);
  float* c0S = (float*)(ws + WS_C0S);
  float* c1S = (float*)(ws + WS_C1S);
  u16* H0M   = (u16*)(ws + WS_H0M);
  u16* V1M   = (u16*)(ws + WS_V1M);
  float* P   = (float*)(ws + WS_ZT);    // aliases Zt (dead at head time)

  whb_kernel<<<256, 256, 0, stream>>>(Wh0, Wh1, whb0, whb1);

  for (int p = 0; p < 4; ++p) {
    int t0 = p * 64;
    zgemm_kernel<1, 128><<<2048, 256, 0, stream>>>(x, Wi0, b0, Zt, t0);
    rec_kernel<<<8, 512, 0, stream>>>(Zt, whb0, c0, h0, c0S,
                                      ys0p + (size_t)63 * 32768, ys0p,
                                      out + 1160, out + 33928, p == 0, p == 3);
    zgemm_kernel<0, 256><<<2048, 256, 0, stream>>>(ys0p, Wi1, b1, Zt, t0);
    rec_kernel<<<8, 512, 0, stream>>>(Zt, whb1, c1, h1, c1S,
                                      (p == 0) ? ys1 : ys1 + (size_t)(t0 - 1) * 32768,
                                      ys1 + (size_t)t0 * 32768,
                                      out + 66696, out + 99464, p == 0, p == 3);
  }

  head_gemm_kernel<<<512, 256, 0, stream>>>(ys1, Wv0, Wm0, P);
  head_reduce_kernel<<<512, 256, 0, stream>>>(P, bv0, bm0, H0M);
  head_mid_kernel<<<16, 256, 0, stream>>>(H0M, Wv1, Wm1, bv1, bm1, V1M);
  head_final_kernel<<<1, 1024, 0, stream>>>(V1M, Wv2, bv2, Wm2, bm2, lstd, out);
}